// Round 2
// baseline (306.095 us; speedup 1.0000x reference)
//
#include <hip/hip_runtime.h>

// RF grid-sample DAS beamforming, round 2.
// Shapes: d_tx[4,512,256] d_rx[128,512,256] apod[128,512,256] rf[4,128,3072] t0[4]
// out[4,512,256] fp32.
//
// Changes vs round 1:
//  - LDS holds rf as PACKED BF16 PAIRS: word i of angle a = (bf16(rf[i]), bf16(rf[i+1])).
//    A linear-interp tap-pair is ONE aligned ds_read_b32 (was ds_read2_b32 = 2 LDS
//    accesses). Halves LDS pipe cycles + bank-conflict exposure. Rounded-to-nearest
//    (+0x8000 before truncate); error budget ~0.1 vs 0.52 threshold.
//  - PXT 8->4, TILES 32->64, grid 512->1024 blocks: 3 blocks/CU resident (48 KB LDS
//    allows floor(160/48)=3), was 2/CU.
//  - Register prefetch of next element's rf row issued before the gather phase
//    (software pipeline) so staging global latency hides behind gather.
//  - Data range: delays in [0, 3070) => i0<=3069, i1<=3070: always in-range, and
//    delay>=0 so (int) truncation == floor. Pair word 3071 is garbage but never read.

#define A_N 4
#define E_N 128
#define S_N 3072
#define NPIX_N (512 * 256)
#define TPB 512
#define PXT 4
#define TILE (TPB * PXT)           // 2048 pixels per block
#define TILES (NPIX_N / TILE)      // 64
#define ESPLIT 16
#define EPB (E_N / ESPLIT)         // 8 elements per block
#define NPK (A_N * S_N)            // 12288 packed words = 48 KB
#define GRP 6                      // uint4 staging groups per thread (3072/512)

__global__ __launch_bounds__(TPB, 6) void das_kernel(
    const float* __restrict__ d_tx, const float* __restrict__ d_rx,
    const float* __restrict__ apod, const float* __restrict__ rf,
    const float* __restrict__ t0,  float* __restrict__ out)
{
    __shared__ unsigned lds_pk[NPK];   // 48 KB
    const int tid = threadIdx.x;
    const int px0 = blockIdx.x * TILE + tid;
    const int e0  = blockIdx.y * EPB;

    // Staging source offsets (rf element units, e-term excluded: addr = off + e*S_N).
    // uint4 #(g*TPB+tid) covers packed words [4*idx, 4*idx+4) of the 4x3072 LDS image;
    // needs rf elements i..i+4 of angle a (extra element clamped at row end; that
    // pair word is never gathered).
    int off[GRP], exoff[GRP];
#pragma unroll
    for (int g = 0; g < GRP; ++g) {
        int idx = g * TPB + tid;            // uint4 index in [0,3072)
        int a   = idx / (S_N / 4);          // 768 uint4 per angle row
        int i   = (idx - a * (S_N / 4)) * 4;
        off[g]   = a * (E_N * S_N) + i;
        exoff[g] = a * (E_N * S_N) + min(i + 4, S_N - 1);
    }

    float acc[A_N][PXT];
    float dta[A_N][PXT];
#pragma unroll
    for (int a = 0; a < A_N; ++a) {
        const float t0a = t0[a];
#pragma unroll
        for (int k = 0; k < PXT; ++k) {
            dta[a][k] = d_tx[a * NPIX_N + px0 + k * TPB] - t0a;
            acc[a][k] = 0.0f;
        }
    }

    // Prefetch first element's rf rows into registers.
    float4 pf[GRP]; float pfx[GRP];
    {
        const float* p = rf + (size_t)e0 * S_N;
#pragma unroll
        for (int g = 0; g < GRP; ++g) {
            pf[g]  = *(const float4*)(p + off[g]);
            pfx[g] = p[exoff[g]];
        }
    }

    for (int ei = 0; ei < EPB; ++ei) {
        const int e = e0 + ei;
        __syncthreads();   // previous iteration's gathers done before overwrite
        // Stage: convert prefetched floats to rounded bf16 pairs, write 16B chunks.
#pragma unroll
        for (int g = 0; g < GRP; ++g) {
            unsigned r0 = __float_as_uint(pf[g].x) + 0x8000u;
            unsigned r1 = __float_as_uint(pf[g].y) + 0x8000u;
            unsigned r2 = __float_as_uint(pf[g].z) + 0x8000u;
            unsigned r3 = __float_as_uint(pf[g].w) + 0x8000u;
            unsigned r4 = __float_as_uint(pfx[g])  + 0x8000u;
            uint4 w;
            w.x = (r0 >> 16) | (r1 & 0xffff0000u);
            w.y = (r1 >> 16) | (r2 & 0xffff0000u);
            w.z = (r2 >> 16) | (r3 & 0xffff0000u);
            w.w = (r3 >> 16) | (r4 & 0xffff0000u);
            ((uint4*)lds_pk)[g * TPB + tid] = w;
        }
        __syncthreads();

        // Issue next element's prefetch before gathering (hide global latency).
        if (ei + 1 < EPB) {
            const float* p = rf + (size_t)(e + 1) * S_N;
#pragma unroll
            for (int g = 0; g < GRP; ++g) {
                pf[g]  = *(const float4*)(p + off[g]);
                pfx[g] = p[exoff[g]];
            }
        }

        const float* __restrict__ drx_row = d_rx + (size_t)e * NPIX_N;
        const float* __restrict__ ap_row  = apod + (size_t)e * NPIX_N;
#pragma unroll
        for (int k = 0; k < PXT; ++k) {
            const int p = px0 + k * TPB;
            const float drx = drx_row[p];
            const float ap  = ap_row[p];
#pragma unroll
            for (int a = 0; a < A_N; ++a) {
                float delay = dta[a][k] + drx;
                int i0 = (int)delay;                 // trunc == floor (delay >= 0)
                float w = delay - (float)i0;
                unsigned u = lds_pk[a * S_N + i0];   // one ds_read_b32: both taps
                float v0 = __uint_as_float(u << 16);
                float v1 = __uint_as_float(u & 0xffff0000u);
                acc[a][k] += ap * (v0 + w * (v1 - v0));
            }
        }
    }

#pragma unroll
    for (int a = 0; a < A_N; ++a)
#pragma unroll
        for (int k = 0; k < PXT; ++k)
            atomicAdd(&out[a * NPIX_N + px0 + k * TPB], acc[a][k]);
}

extern "C" void kernel_launch(void* const* d_in, const int* in_sizes, int n_in,
                              void* d_out, int out_size, void* d_ws, size_t ws_size,
                              hipStream_t stream) {
    const float* d_tx = (const float*)d_in[0];
    const float* d_rx = (const float*)d_in[1];
    const float* apod = (const float*)d_in[2];
    const float* rf   = (const float*)d_in[3];
    const float* t0   = (const float*)d_in[4];
    float* out = (float*)d_out;

    hipMemsetAsync(out, 0, (size_t)out_size * sizeof(float), stream);
    dim3 grid(TILES, ESPLIT);
    das_kernel<<<grid, TPB, 0, stream>>>(d_tx, d_rx, apod, rf, t0, out);
}

// Round 3
// 255.653 us; speedup vs baseline: 1.1973x; 1.1973x over previous
//
#include <hip/hip_runtime.h>

// RF grid-sample DAS beamforming, round 3.
// Shapes: d_tx[4,512,256] d_rx[128,512,256] apod[128,512,256] rf[4,128,3072] t0[4]
// out[4,512,256] fp32.
//
// Round-2 post-mortem: TILES=64 doubled rf staging requests (192->402 MB) and the
// delta appeared 1:1 in FETCH_SIZE -> traffic-bound regression. bf16 pair-packing
// itself halved LDS bank conflicts as predicted (1.04e7 -> 5.2e6). Keep packing,
// revert geometry, make rf reuse structural:
//
//  - grid(ESPLIT=16, TILES=32), e-chunk = blockIdx.x (FAST dim). Linear block ids
//    round-robin across 8 XCDs, so XCD k gets only e-chunks {k, k+8}: rf working
//    set per XCD = 2 x 393 KB = 786 KB << 4 MB L2. Staging for all but the first
//    tile-block per e-chunk hits L2 (~200 cyc), not HBM (~900 cyc).
//  - LDS: rf as packed bf16 pairs (word i = (bf16 rf[i], bf16 rf[i+1])): one
//    ds_read_b32 per linear-interp tap-pair. Rounded (+0x8000); absmax ~0.125
//    vs 0.52 threshold.
//  - Register prefetch of next element's rf row before the gather phase.
//  - Data range: delays in [0,3070) => i0<=3069, always in-range; (int) trunc ==
//    floor since delay>=0. Pair word 3071 never read.

#define A_N 4
#define E_N 128
#define S_N 3072
#define NPIX_N (512 * 256)
#define TPB 512
#define PXT 8
#define TILE (TPB * PXT)           // 4096 pixels per block
#define TILES (NPIX_N / TILE)      // 32
#define ESPLIT 16
#define EPB (E_N / ESPLIT)         // 8 elements per block
#define NPK (A_N * S_N)            // 12288 packed words = 48 KB
#define GRP 6                      // uint4 staging groups per thread (3072/512)

__global__ __launch_bounds__(TPB, 4) void das_kernel(
    const float* __restrict__ d_tx, const float* __restrict__ d_rx,
    const float* __restrict__ apod, const float* __restrict__ rf,
    const float* __restrict__ t0,  float* __restrict__ out)
{
    __shared__ unsigned lds_pk[NPK];   // 48 KB
    const int tid = threadIdx.x;
    const int px0 = blockIdx.y * TILE + tid;   // tile = blockIdx.y (slow dim)
    const int e0  = blockIdx.x * EPB;          // e-chunk = blockIdx.x (fast dim -> XCD affinity)

    // Staging source offsets (rf element units; full addr = off + e*S_N).
    int off[GRP], exoff[GRP];
#pragma unroll
    for (int g = 0; g < GRP; ++g) {
        int idx = g * TPB + tid;            // uint4 index in [0,3072)
        int a   = idx / (S_N / 4);          // 768 uint4 per angle row
        int i   = (idx - a * (S_N / 4)) * 4;
        off[g]   = a * (E_N * S_N) + i;
        exoff[g] = a * (E_N * S_N) + min(i + 4, S_N - 1);
    }

    float acc[A_N][PXT];
    float dta[A_N][PXT];
#pragma unroll
    for (int a = 0; a < A_N; ++a) {
        const float t0a = t0[a];
#pragma unroll
        for (int k = 0; k < PXT; ++k) {
            dta[a][k] = d_tx[a * NPIX_N + px0 + k * TPB] - t0a;
            acc[a][k] = 0.0f;
        }
    }

    // Prefetch first element's rf rows into registers.
    float4 pf[GRP]; float pfx[GRP];
    {
        const float* p = rf + (size_t)e0 * S_N;
#pragma unroll
        for (int g = 0; g < GRP; ++g) {
            pf[g]  = *(const float4*)(p + off[g]);
            pfx[g] = p[exoff[g]];
        }
    }

    for (int ei = 0; ei < EPB; ++ei) {
        const int e = e0 + ei;
        __syncthreads();   // previous iteration's gathers done before overwrite
        // Stage: convert prefetched floats to rounded bf16 pairs, write 16B chunks.
#pragma unroll
        for (int g = 0; g < GRP; ++g) {
            unsigned r0 = __float_as_uint(pf[g].x) + 0x8000u;
            unsigned r1 = __float_as_uint(pf[g].y) + 0x8000u;
            unsigned r2 = __float_as_uint(pf[g].z) + 0x8000u;
            unsigned r3 = __float_as_uint(pf[g].w) + 0x8000u;
            unsigned r4 = __float_as_uint(pfx[g])  + 0x8000u;
            uint4 w;
            w.x = (r0 >> 16) | (r1 & 0xffff0000u);
            w.y = (r1 >> 16) | (r2 & 0xffff0000u);
            w.z = (r2 >> 16) | (r3 & 0xffff0000u);
            w.w = (r3 >> 16) | (r4 & 0xffff0000u);
            ((uint4*)lds_pk)[g * TPB + tid] = w;
        }
        __syncthreads();

        // Issue next element's prefetch before gathering (hide global latency).
        if (ei + 1 < EPB) {
            const float* p = rf + (size_t)(e + 1) * S_N;
#pragma unroll
            for (int g = 0; g < GRP; ++g) {
                pf[g]  = *(const float4*)(p + off[g]);
                pfx[g] = p[exoff[g]];
            }
        }

        const float* __restrict__ drx_row = d_rx + (size_t)e * NPIX_N;
        const float* __restrict__ ap_row  = apod + (size_t)e * NPIX_N;
#pragma unroll
        for (int k = 0; k < PXT; ++k) {
            const int p = px0 + k * TPB;
            const float drx = drx_row[p];
            const float ap  = ap_row[p];
#pragma unroll
            for (int a = 0; a < A_N; ++a) {
                float delay = dta[a][k] + drx;
                int i0 = (int)delay;                 // trunc == floor (delay >= 0)
                float w = delay - (float)i0;
                unsigned u = lds_pk[a * S_N + i0];   // one ds_read_b32: both taps
                float v0 = __uint_as_float(u << 16);
                float v1 = __uint_as_float(u & 0xffff0000u);
                acc[a][k] += ap * (v0 + w * (v1 - v0));
            }
        }
    }

#pragma unroll
    for (int a = 0; a < A_N; ++a)
#pragma unroll
        for (int k = 0; k < PXT; ++k)
            atomicAdd(&out[a * NPIX_N + px0 + k * TPB], acc[a][k]);
}

extern "C" void kernel_launch(void* const* d_in, const int* in_sizes, int n_in,
                              void* d_out, int out_size, void* d_ws, size_t ws_size,
                              hipStream_t stream) {
    const float* d_tx = (const float*)d_in[0];
    const float* d_rx = (const float*)d_in[1];
    const float* apod = (const float*)d_in[2];
    const float* rf   = (const float*)d_in[3];
    const float* t0   = (const float*)d_in[4];
    float* out = (float*)d_out;

    hipMemsetAsync(out, 0, (size_t)out_size * sizeof(float), stream);
    dim3 grid(ESPLIT, TILES);   // e-chunk fast -> same e-chunk blocks share an XCD
    das_kernel<<<grid, TPB, 0, stream>>>(d_tx, d_rx, apod, rf, t0, out);
}